// Round 12
// baseline (470.740 us; speedup 1.0000x reference)
//
#include <hip/hip_runtime.h>
#include <hip/hip_cooperative_groups.h>
#include <cstdint>
#include <cstddef>

#define I_DIM 1024
#define O_DIM 1024
#define B_DIM 128
#define T_DIM 100
#define PANEL 32768  // fragment-tiled panel stride (ushorts) = 64q*64lane*8
#define QSTep 512    // per-q stride (ushorts) = 64 lanes * 8
#define NCOOP 512    // persistent cooperative grid (guaranteed co-resident)

namespace cg = cooperative_groups;

typedef __attribute__((ext_vector_type(8))) __bf16 bf16x8;
typedef __attribute__((ext_vector_type(16))) float f32x16;

__device__ __forceinline__ unsigned short bf16rn(float x) {
  unsigned u = __float_as_uint(x);
  unsigned r = u + 0x7FFFu + ((u >> 16) & 1u);
  return (unsigned short)(r >> 16);
}
__device__ __forceinline__ void split2(float x, unsigned short& h,
                                       unsigned short& l) {
  h = bf16rn(x);
  float hf = __uint_as_float(((unsigned)h) << 16);
  l = bf16rn(x - hf);
}

// ---------------------------------------------------------------------------
// prep unit (R10-validated): u<256 = split_wT tile (+norm partials),
// u>=256 = xsplit quarter-panel.
// ---------------------------------------------------------------------------
__device__ __forceinline__ void prep_unit(
    int u, int tid, const float* __restrict__ w, const float* __restrict__ x,
    unsigned short* __restrict__ wTth, unsigned short* __restrict__ wTtl,
    unsigned short* __restrict__ xth, unsigned short* __restrict__ xtl,
    double* __restrict__ normpart, float (*tile)[65], double (*red)[64]) {
  if (u < 256) {
    const int a0 = (u >> 4) * 64, o0 = (u & 15) * 64;
    const int tr = tid >> 4, tc4 = (tid & 15) * 4;
#pragma unroll
    for (int rr = 0; rr < 64; rr += 16) {
      float4 vv = *(const float4*)&w[(size_t)(a0 + tr + rr) * O_DIM + o0 + tc4];
      tile[tr + rr][tc4 + 0] = vv.x;
      tile[tr + rr][tc4 + 1] = vv.y;
      tile[tr + rr][tc4 + 2] = vv.z;
      tile[tr + rr][tc4 + 3] = vv.w;
    }
    __syncthreads();
    {
      const int ol = tid & 63, seg = tid >> 6;
      double s = 0.0;
#pragma unroll
      for (int i = 0; i < 16; ++i) {
        double vv = (double)tile[seg * 16 + i][ol];
        s += vv * vv;
      }
      red[seg][ol] = s;
    }
    const int q = (a0 >> 4) + (tc4 >> 4);
    const int kh = (tc4 >> 3) & 1;
    const int inner = tc4 & 7;
#pragma unroll
    for (int rr = 0; rr < 64; rr += 16) {
      int o = o0 + tr + rr;
      unsigned short hh[4], ll[4];
#pragma unroll
      for (int j = 0; j < 4; ++j) split2(tile[tc4 + j][tr + rr], hh[j], ll[j]);
      int l = (o & 31) + 32 * kh;
      size_t base = ((size_t)(o >> 5) * PANEL) + (size_t)q * QSTep +
                    (size_t)l * 8 + inner;
      *(ushort4*)&wTth[base] = make_ushort4(hh[0], hh[1], hh[2], hh[3]);
      *(ushort4*)&wTtl[base] = make_ushort4(ll[0], ll[1], ll[2], ll[3]);
    }
    __syncthreads();
    if (tid < 64)
      normpart[(size_t)(a0 >> 6) * O_DIM + o0 + tid] =
          red[0][tid] + red[1][tid] + red[2][tid] + red[3][tid];
  } else {
    const int p = (u - 256) >> 2, sub = (u - 256) & 3;
    const int wq = tid >> 6, lane = tid & 63;
    const int row = lane & 31, kh = lane >> 5;
    const float* src = x + (size_t)(p * 32 + row) * I_DIM + kh * 8;
#pragma unroll
    for (int i = sub * 4; i < sub * 4 + 4; ++i) {
      const int q = i * 4 + wq;
      const float* s = src + q * 16;
      float4 v0 = *(const float4*)(s);
      float4 v1 = *(const float4*)(s + 4);
      unsigned short hh[8], ll[8];
      split2(v0.x, hh[0], ll[0]);
      split2(v0.y, hh[1], ll[1]);
      split2(v0.z, hh[2], ll[2]);
      split2(v0.w, hh[3], ll[3]);
      split2(v1.x, hh[4], ll[4]);
      split2(v1.y, hh[5], ll[5]);
      split2(v1.z, hh[6], ll[6]);
      split2(v1.w, hh[7], ll[7]);
      size_t base = ((size_t)p * PANEL) + (size_t)q * QSTep + (size_t)lane * 8;
      *(ushort4*)&xth[base] = make_ushort4(hh[0], hh[1], hh[2], hh[3]);
      *(ushort4*)&xth[base + 4] = make_ushort4(hh[4], hh[5], hh[6], hh[7]);
      *(ushort4*)&xtl[base] = make_ushort4(ll[0], ll[1], ll[2], ll[3]);
      *(ushort4*)&xtl[base + 4] = make_ushort4(ll[4], ll[5], ll[6], ll[7]);
    }
  }
}

// ---------------------------------------------------------------------------
// gemm unit (R10-validated): id<800 = hgemm 128x128 WG tile w/ XCD swizzle;
// id>=800 = mbuild. 4 waves, wave tile 64x64, distance-1 prefetch,
// per-acc MFMA order (q asc; hh,hl,lh) -> bit-identical h, M.
// ---------------------------------------------------------------------------
__device__ __forceinline__ void gemm_unit(
    int id, int tid, const unsigned short* __restrict__ xth,
    const unsigned short* __restrict__ xtl,
    const unsigned short* __restrict__ wTth,
    const unsigned short* __restrict__ wTtl, const float* __restrict__ v,
    const float* __restrict__ beta_p, float* __restrict__ h,
    float* __restrict__ M) {
  const int wv = tid >> 6, lane = tid & 63;
  const int wm = wv >> 1, wn = wv & 1;
  const int lm = lane & 31, lkh = lane >> 5;
  const bool is_h = id < 800;
  int rbase, cbase;
  const unsigned short *Ah_src, *Al_src;
  if (is_h) {
    rbase = (id % 100) * 128;
    cbase = (id / 100) * 128;
    Ah_src = xth;
    Al_src = xtl;
  } else {
    rbase = ((id - 800) >> 3) * 128;
    cbase = ((id - 800) & 7) * 128;
    Ah_src = wTth;
    Al_src = wTtl;
  }
  f32x16 acc[2][2];
#pragma unroll
  for (int a = 0; a < 2; ++a)
#pragma unroll
    for (int b = 0; b < 2; ++b)
#pragma unroll
      for (int e = 0; e < 16; ++e) acc[a][b][e] = 0.f;
  const unsigned short *pah[2], *pal[2], *pbh[2], *pbl[2];
#pragma unroll
  for (int t = 0; t < 2; ++t) {
    size_t offA =
        ((size_t)((rbase >> 5) + wm * 2 + t) * PANEL) + (size_t)lane * 8;
    size_t offB =
        ((size_t)((cbase >> 5) + wn * 2 + t) * PANEL) + (size_t)lane * 8;
    pah[t] = Ah_src + offA;
    pal[t] = Al_src + offA;
    pbh[t] = wTth + offB;
    pbl[t] = wTtl + offB;
  }
  bf16x8 fah[2][2], fal[2][2], fbh[2][2], fbl[2][2];
#pragma unroll
  for (int t = 0; t < 2; ++t) {
    fah[0][t] = *(const bf16x8*)(pah[t]);
    fal[0][t] = *(const bf16x8*)(pal[t]);
    fbh[0][t] = *(const bf16x8*)(pbh[t]);
    fbl[0][t] = *(const bf16x8*)(pbl[t]);
  }
#pragma unroll 2
  for (int q = 0; q < 64; ++q) {
    const int cb = q & 1;
    if (q < 63) {
      size_t d = (size_t)(q + 1) * QSTep;
#pragma unroll
      for (int t = 0; t < 2; ++t) {
        fah[cb ^ 1][t] = *(const bf16x8*)(pah[t] + d);
        fal[cb ^ 1][t] = *(const bf16x8*)(pal[t] + d);
        fbh[cb ^ 1][t] = *(const bf16x8*)(pbh[t] + d);
        fbl[cb ^ 1][t] = *(const bf16x8*)(pbl[t] + d);
      }
    }
#pragma unroll
    for (int mt = 0; mt < 2; ++mt)
#pragma unroll
      for (int nt = 0; nt < 2; ++nt)
        acc[mt][nt] = __builtin_amdgcn_mfma_f32_32x32x16_bf16(
            fah[cb][mt], fbh[cb][nt], acc[mt][nt], 0, 0, 0);
#pragma unroll
    for (int mt = 0; mt < 2; ++mt)
#pragma unroll
      for (int nt = 0; nt < 2; ++nt)
        acc[mt][nt] = __builtin_amdgcn_mfma_f32_32x32x16_bf16(
            fah[cb][mt], fbl[cb][nt], acc[mt][nt], 0, 0, 0);
#pragma unroll
    for (int mt = 0; mt < 2; ++mt)
#pragma unroll
      for (int nt = 0; nt < 2; ++nt)
        acc[mt][nt] = __builtin_amdgcn_mfma_f32_32x32x16_bf16(
            fal[cb][mt], fbh[cb][nt], acc[mt][nt], 0, 0, 0);
  }
  if (is_h) {
#pragma unroll
    for (int mt = 0; mt < 2; ++mt)
#pragma unroll
      for (int nt = 0; nt < 2; ++nt) {
        int col = cbase + wn * 64 + nt * 32 + lm;
#pragma unroll
        for (int r = 0; r < 16; ++r) {
          int row =
              rbase + wm * 64 + mt * 32 + (r & 3) + 8 * (r >> 2) + 4 * lkh;
          h[(size_t)row * O_DIM + col] = acc[mt][nt][r];
        }
      }
  } else {
    const float beta = beta_p[0];
    const float ombeta = 1.0f - beta;
#pragma unroll
    for (int mt = 0; mt < 2; ++mt)
#pragma unroll
      for (int nt = 0; nt < 2; ++nt) {
        int col = cbase + wn * 64 + nt * 32 + lm;
#pragma unroll
        for (int r = 0; r < 16; ++r) {
          int row =
              rbase + wm * 64 + mt * 32 + (r & 3) + 8 * (r >> 2) + 4 * lkh;
          M[(size_t)row * O_DIM + col] =
              ombeta * v[(size_t)row * O_DIM + col] - beta * acc[mt][nt][r];
        }
      }
  }
}

// ---------------------------------------------------------------------------
// Cooperative fused kernel: 512 persistent WGs (guaranteed co-resident:
// <=256 regs via launch_bounds(256,2), 18.7 KB LDS -> >=2 WGs/CU).
// Phase 1 strides 1856 prep units; grid.sync (+device fences for cross-XCD
// L2); phase 2 strides 864 gemm units.
// ---------------------------------------------------------------------------
__global__ __launch_bounds__(256, 2) void fused_kernel(
    const float* __restrict__ w, const float* __restrict__ x,
    unsigned short* __restrict__ wTth, unsigned short* __restrict__ wTtl,
    unsigned short* __restrict__ xth, unsigned short* __restrict__ xtl,
    double* __restrict__ normpart, const float* __restrict__ v,
    const float* __restrict__ beta_p, float* __restrict__ h,
    float* __restrict__ M, int* __restrict__ done) {
  __shared__ float tile[64][65];
  __shared__ double red[4][64];
  const int tid = threadIdx.x;
  if (blockIdx.x == 0 && tid == 0) *done = 0;
  for (int u = blockIdx.x; u < 1856; u += NCOOP)
    prep_unit(u, tid, w, x, wTth, wTtl, xth, xtl, normpart, tile, red);
  __threadfence();
  cg::this_grid().sync();
  __threadfence();
  for (int id = blockIdx.x; id < 864; id += NCOOP)
    gemm_unit(id, tid, xth, xtl, wTth, wTtl, v, beta_p, h, M);
}

// ---- standalone fallback kernels (R10 exact launch shapes) ----
__global__ __launch_bounds__(256) void prep_kernel(
    const float* __restrict__ w, const float* __restrict__ x,
    unsigned short* __restrict__ wTth, unsigned short* __restrict__ wTtl,
    unsigned short* __restrict__ xth, unsigned short* __restrict__ xtl,
    double* __restrict__ normpart, int* __restrict__ done) {
  __shared__ float tile[64][65];
  __shared__ double red[4][64];
  if (blockIdx.x == 0 && threadIdx.x == 0) *done = 0;
  prep_unit(blockIdx.x, threadIdx.x, w, x, wTth, wTtl, xth, xtl, normpart,
            tile, red);
}

__global__ __launch_bounds__(256, 3) void gemm_kernel(
    const unsigned short* __restrict__ xth,
    const unsigned short* __restrict__ xtl,
    const unsigned short* __restrict__ wTth,
    const unsigned short* __restrict__ wTtl, const float* __restrict__ v,
    const float* __restrict__ beta_p, float* __restrict__ h,
    float* __restrict__ M) {
  gemm_unit(blockIdx.x, threadIdx.x, xth, xtl, wTth, wTtl, v, beta_p, h, M);
}

// ---------------------------------------------------------------------------
// Scan (R10-validated): ONE WAVE per batch, 16 neurons/lane, barrier-free,
// ballot spike masks in registers. Threshold precomputed:
// spike iff mem > b*(norm+1e-8) (b>0; shift ~1e-16). Folded finalize.
// ---------------------------------------------------------------------------
__global__ __launch_bounds__(64) void scan_kernel(
    const float* __restrict__ h, const float* __restrict__ M,
    const double* __restrict__ normpart, const float* __restrict__ bvec,
    const float* __restrict__ beta_p, float* __restrict__ out,
    int* __restrict__ wgcnt, int* __restrict__ done) {
  const int b = blockIdx.x, lane = threadIdx.x;
  const double beta = (double)beta_p[0];
  const double ombeta = 1.0 - beta;
  double mem[4][4], thr[4][4];
  unsigned long long pmask[4][4];
#pragma unroll
  for (int k = 0; k < 4; ++k)
#pragma unroll
    for (int j = 0; j < 4; ++j) {
      const int o = 256 * k + 4 * lane + j;
      mem[k][j] = 0.0;
      double s = 0.0;
#pragma unroll
      for (int g = 0; g < 16; ++g) s += normpart[(size_t)g * O_DIM + o];
      thr[k][j] = (s + 1e-8) * (double)bvec[o];
      pmask[k][j] = 0ull;
    }
  const float* hb = h + (size_t)b * T_DIM * O_DIM;
  float* obp = out + (size_t)b * T_DIM * O_DIM;
  float4 hv0[4], hv1[4];
#pragma unroll
  for (int k = 0; k < 4; ++k) {
    hv0[k] = *(const float4*)&hb[256 * k + 4 * lane];
    hv1[k] = *(const float4*)&hb[O_DIM + 256 * k + 4 * lane];
  }
  for (int t = 0; t < T_DIM; ++t) {
    float4 hv2[4];
#pragma unroll
    for (int k = 0; k < 4; ++k) hv2[k] = make_float4(0.f, 0.f, 0.f, 0.f);
    if (t + 2 < T_DIM) {
#pragma unroll
      for (int k = 0; k < 4; ++k)
        hv2[k] =
            *(const float4*)&hb[(size_t)(t + 2) * O_DIM + 256 * k + 4 * lane];
    }
    double lat[4][4] = {};
#pragma unroll
    for (int k2 = 0; k2 < 4; ++k2)
#pragma unroll
      for (int j2 = 0; j2 < 4; ++j2) {
        unsigned long long m = pmask[k2][j2];
        while (m) {
          const int p = (int)__builtin_ctzll(m);
          m &= m - 1;
          const int i = 256 * k2 + 4 * p + j2;
          const float* Mr = M + (size_t)i * O_DIM + 4 * lane;
#pragma unroll
          for (int k = 0; k < 4; ++k) {
            float4 mv = *(const float4*)(Mr + 256 * k);
            lat[k][0] += (double)mv.x;
            lat[k][1] += (double)mv.y;
            lat[k][2] += (double)mv.z;
            lat[k][3] += (double)mv.w;
          }
        }
      }
    int cnt = 0;
#pragma unroll
    for (int k = 0; k < 4; ++k) {
      const float hvv[4] = {hv0[k].x, hv0[k].y, hv0[k].z, hv0[k].w};
      float os[4];
#pragma unroll
      for (int j = 0; j < 4; ++j) {
        mem[k][j] = mem[k][j] * beta + (double)hvv[j] * ombeta + lat[k][j];
        bool s = mem[k][j] > thr[k][j];
        os[j] = s ? 1.0f : 0.0f;
        unsigned long long mk = __ballot(s);
        pmask[k][j] = mk;
        cnt += (int)__popcll(mk);
      }
      *(float4*)&obp[(size_t)t * O_DIM + 256 * k + 4 * lane] =
          make_float4(os[0], os[1], os[2], os[3]);
      hv0[k] = hv1[k];
      hv1[k] = hv2[k];
    }
    if (lane == 0) wgcnt[b * T_DIM + t] = cnt;
  }
  __threadfence();
  int old = 0;
  if (lane == 0) old = atomicAdd(done, 1);
  old = __shfl(old, 0, 64);
  if (old == B_DIM - 1) {
    __threadfence();
    long long tsum = 0;
    int mx = 0;
    for (int t = lane; t < T_DIM; t += 64) {
      int st = 0;
      for (int bb = 0; bb < B_DIM; ++bb) st += wgcnt[bb * T_DIM + t];
      tsum += st;
      if (st > mx) mx = st;
    }
#pragma unroll
    for (int off = 32; off > 0; off >>= 1) {
      tsum += __shfl_down((long long)tsum, off, 64);
      int m2 = __shfl_down(mx, off, 64);
      if (m2 > mx) mx = m2;
    }
    if (lane == 0) {
      const double N = (double)B_DIM * T_DIM * O_DIM;
      out[(size_t)B_DIM * T_DIM * O_DIM] = (float)(0.5 * (double)tsum / N);
      out[(size_t)B_DIM * T_DIM * O_DIM + 1] =
          (float)((double)mx / (double)(B_DIM * O_DIM));
    }
  }
}

extern "C" void kernel_launch(void* const* d_in, const int* in_sizes, int n_in,
                              void* d_out, int out_size, void* d_ws,
                              size_t ws_size, hipStream_t stream) {
  const float* x = (const float*)d_in[0];
  const float* w = (const float*)d_in[1];
  const float* v = (const float*)d_in[2];
  const float* beta = (const float*)d_in[3];
  const float* b = (const float*)d_in[4];
  float* out = (float*)d_out;

  char* ws = (char*)d_ws;
  const size_t OFF_M = 0;            // 4 MB
  const size_t OFF_H = 4194304;      // 50 MB
  const size_t OFF_WTH = 56623104;   // 2 MB
  const size_t OFF_WTL = 58720256;   // 2 MB
  const size_t OFF_NP = 60817408;    // 128 KB normpart
  const size_t OFF_DONE = 60948480;  // 512 B done counter
  const size_t OFF_XTH = 60948992;   // 25 MB
  const size_t OFF_XTL = 87163392;   // 25 MB -> end 113377792 (fits, proven)
  float* M = (float*)(ws + OFF_M);
  float* h = (float*)(ws + OFF_H);
  unsigned short* wTth = (unsigned short*)(ws + OFF_WTH);
  unsigned short* wTtl = (unsigned short*)(ws + OFF_WTL);
  double* normpart = (double*)(ws + OFF_NP);
  int* done = (int*)(ws + OFF_DONE);
  unsigned short* xth = (unsigned short*)(ws + OFF_XTH);
  unsigned short* xtl = (unsigned short*)(ws + OFF_XTL);
  int* wgcnt = (int*)(ws + OFF_XTH);  // reuses dead xt region

  const float* wp = w;
  const float* xp = x;
  const float* vp = v;
  const float* bp = beta;
  void* args[] = {(void*)&wp,   (void*)&xp,  (void*)&wTth,     (void*)&wTtl,
                  (void*)&xth,  (void*)&xtl, (void*)&normpart, (void*)&vp,
                  (void*)&bp,   (void*)&h,   (void*)&M,        (void*)&done};
  hipError_t err = hipLaunchCooperativeKernel(
      (const void*)fused_kernel, dim3(NCOOP), dim3(256), args, 0, stream);
  if (err != hipSuccess) {
    // fallback: R10-validated separate launches (identical outputs)
    hipLaunchKernelGGL(prep_kernel, dim3(1856), dim3(256), 0, stream, w, x,
                       wTth, wTtl, xth, xtl, normpart, done);
    hipLaunchKernelGGL(gemm_kernel, dim3(864), dim3(256), 0, stream, xth, xtl,
                       wTth, wTtl, v, beta, h, M);
  }
  hipLaunchKernelGGL(scan_kernel, dim3(128), dim3(64), 0, stream, h, M,
                     normpart, b, beta, out, wgcnt, done);
}